// Round 1
// baseline (8584.587 us; speedup 1.0000x reference)
//
#include <hip/hip_runtime.h>
#include <hip/hip_bf16.h>
#include <stdint.h>

typedef short bf16x8 __attribute__((ext_vector_type(8)));
typedef float f32x4 __attribute__((ext_vector_type(4)));

#define B_ 16384
#define D_ 1024
#define H_ 1024
#define E_ 16
#define C_ 1024
#define TAU 1.0e-3f

// ---------- helpers ----------
__device__ __forceinline__ uint16_t f2bf(float f){
  uint32_t u = __float_as_uint(f);
  return (uint16_t)((u + 0x7FFFu + ((u >> 16) & 1u)) >> 16);
}
__device__ __forceinline__ float bf2f(uint16_t h){
  return __uint_as_float(((uint32_t)h) << 16);
}
__device__ __forceinline__ void glds16(const void* g, void* l){
  typedef __attribute__((address_space(1))) unsigned int* gp_t;
  typedef __attribute__((address_space(3))) unsigned int* lp_t;
  __builtin_amdgcn_global_load_lds((gp_t)(uintptr_t)g, (lp_t)(uintptr_t)l, 16, 0, 0);
}

// ---------- cast / split kernels ----------
__global__ void k_cast(const float4* __restrict__ src, ushort4* __restrict__ dst, int n4){
  int i = blockIdx.x*256 + threadIdx.x;
  if (i >= n4) return;
  float4 v = src[i];
  ushort4 o; o.x=f2bf(v.x); o.y=f2bf(v.y); o.z=f2bf(v.z); o.w=f2bf(v.w);
  dst[i] = o;
}

__global__ void k_cast_wall(const float4* __restrict__ We, const float4* __restrict__ Wgen,
                            ushort4* __restrict__ dst){
  int i = blockIdx.x*256 + threadIdx.x;
  if (i >= 4456448) return;
  float4 v = (i < 4194304) ? We[i] : Wgen[i - 4194304];
  ushort4 o; o.x=f2bf(v.x); o.y=f2bf(v.y); o.z=f2bf(v.z); o.w=f2bf(v.w);
  dst[i] = o;
}

__global__ void k_split(const float4* __restrict__ src, ushort4* __restrict__ hi,
                        ushort4* __restrict__ lo, int n4){
  int i = blockIdx.x*256 + threadIdx.x;
  if (i >= n4) return;
  float4 v = src[i];
  ushort4 h, l;
  h.x=f2bf(v.x); l.x=f2bf(v.x - bf2f(h.x));
  h.y=f2bf(v.y); l.y=f2bf(v.y - bf2f(h.y));
  h.z=f2bf(v.z); l.z=f2bf(v.z - bf2f(h.z));
  h.w=f2bf(v.w); l.w=f2bf(v.w - bf2f(h.w));
  hi[i]=h; lo[i]=l;
}

// ---------- gate GEMM1: z = cond @ Wg1^T + bg1, h = gelu(z), split-bf16 x3 ----------
__global__ __launch_bounds__(256) void k_gate_gemm(
    const uint16_t* __restrict__ Ah_g, const uint16_t* __restrict__ Al_g,
    const uint16_t* __restrict__ Bh_g, const uint16_t* __restrict__ Bl_g,
    const float* __restrict__ bg1, float* __restrict__ hbuf){
  __shared__ uint16_t Ah[128*32], Al[128*32], Bh[128*32], Bl[128*32];
  const int tid = threadIdx.x, wv = tid>>6, ln = tid&63;
  const int mt = blockIdx.x>>3, nt = blockIdx.x&7;
  const int wr = wv>>1, wc = wv&1, lr = ln&15, lk = ln>>4;
  f32x4 acc[4][4];
  f32x4 z4 = {0.f,0.f,0.f,0.f};
  #pragma unroll
  for (int m=0;m<4;m++){
    #pragma unroll
    for (int n=0;n<4;n++) acc[m][n] = z4;
  }
  const int rA = mt*128, rB = nt*128;
  const int srow = (ln>>2), scol = (ln&3)*8;
  for (int ks=0; ks<32; ++ks){
    const int k0 = ks*32;
    __syncthreads();
    #pragma unroll
    for (int c2=0;c2<2;c2++){
      int ch = wv + c2*4;
      int r = ch*16 + srow;
      size_t aoff = (size_t)(rA + r)*1024 + k0 + scol;
      size_t boff = (size_t)(rB + r)*1024 + k0 + scol;
      glds16(Ah_g + aoff, (char*)Ah + ch*1024);
      glds16(Al_g + aoff, (char*)Al + ch*1024);
      glds16(Bh_g + boff, (char*)Bh + ch*1024);
      glds16(Bl_g + boff, (char*)Bl + ch*1024);
    }
    asm volatile("s_waitcnt vmcnt(0)" ::: "memory");
    __syncthreads();
    bf16x8 ah[4], al[4], bh[4], bl[4];
    #pragma unroll
    for (int m=0;m<4;m++){
      int r = wr*64 + m*16 + lr;
      ah[m] = *(const bf16x8*)&Ah[r*32 + lk*8];
      al[m] = *(const bf16x8*)&Al[r*32 + lk*8];
    }
    #pragma unroll
    for (int n=0;n<4;n++){
      int r = wc*64 + n*16 + lr;
      bh[n] = *(const bf16x8*)&Bh[r*32 + lk*8];
      bl[n] = *(const bf16x8*)&Bl[r*32 + lk*8];
    }
    #pragma unroll
    for (int m=0;m<4;m++){
      #pragma unroll
      for (int n=0;n<4;n++){
        acc[m][n] = __builtin_amdgcn_mfma_f32_16x16x32_bf16(ah[m], bh[n], acc[m][n], 0,0,0);
        acc[m][n] = __builtin_amdgcn_mfma_f32_16x16x32_bf16(ah[m], bl[n], acc[m][n], 0,0,0);
        acc[m][n] = __builtin_amdgcn_mfma_f32_16x16x32_bf16(al[m], bh[n], acc[m][n], 0,0,0);
      }
    }
  }
  #pragma unroll
  for (int m=0;m<4;m++){
    #pragma unroll
    for (int j=0;j<4;j++){
      int r = rA + wr*64 + m*16 + lk*4 + j;
      #pragma unroll
      for (int n=0;n<4;n++){
        int c = rB + wc*64 + n*16 + lr;
        float z = acc[m][n][j] + bg1[c];
        hbuf[(size_t)r*1024 + c] = 0.5f*z*(1.0f + erff(z*0.70710678118654752f));
      }
    }
  }
}

// ---------- gate stage 2: logits, softmax, top-3, ambiguity flag ----------
__global__ __launch_bounds__(256) void k_gate2(
    const float* __restrict__ hbuf, const float* __restrict__ Wg2,
    const float* __restrict__ bg2, int* __restrict__ tidx,
    float* __restrict__ tprob, int* __restrict__ flags){
  __shared__ float w2[16*1024];
  const int tid = threadIdx.x;
  for (int i = tid; i < 4096; i += 256)
    ((float4*)w2)[i] = ((const float4*)Wg2)[i];
  __syncthreads();
  const int wv = tid>>6, ln = tid&63;
  const int t = blockIdx.x*4 + wv;
  float s[16];
  #pragma unroll
  for (int e2=0;e2<16;e2++) s[e2]=0.f;
  #pragma unroll
  for (int i=0;i<4;i++){
    float4 hv = *(const float4*)&hbuf[(size_t)t*1024 + i*256 + ln*4];
    #pragma unroll
    for (int e2=0;e2<16;e2++){
      float4 w = *(const float4*)&w2[e2*1024 + i*256 + ln*4];
      s[e2] += hv.x*w.x + hv.y*w.y + hv.z*w.z + hv.w*w.w;
    }
  }
  #pragma unroll
  for (int e2=0;e2<16;e2++){
    float v = s[e2];
    #pragma unroll
    for (int off=32; off>0; off>>=1) v += __shfl_xor(v, off);
    s[e2] = v + bg2[e2];
  }
  float v0=-1e30f,v1=-1e30f,v2=-1e30f,v3=-1e30f; int x0=0,x1=0,x2=0,x3=0;
  #pragma unroll
  for (int e2=0;e2<16;e2++){
    float le = s[e2];
    if (le > v0){ v3=v2;x3=x2; v2=v1;x2=x1; v1=v0;x1=x0; v0=le;x0=e2; }
    else if (le > v1){ v3=v2;x3=x2; v2=v1;x2=x1; v1=le;x1=e2; }
    else if (le > v2){ v3=v2;x3=x2; v2=le;x2=e2; }
    else if (le > v3){ v3=le;x3=e2; }
  }
  float den = 0.f;
  #pragma unroll
  for (int e2=0;e2<16;e2++) den += expf(s[e2]-v0);
  if (ln==0){
    tidx[t*3+0]=x0; tidx[t*3+1]=x1; tidx[t*3+2]=x2;
    tprob[t*3+0]=expf(0.f)/den;
    tprob[t*3+1]=expf(v1-v0)/den;
    tprob[t*3+2]=expf(v2-v0)/den;
    flags[t] = ((v2 - v3) < TAU) ? 1 : 0;
  }
}

// ---------- gate refine (f64) for boundary-ambiguous tokens ----------
__global__ void k_refine(const float* __restrict__ cond, const float* __restrict__ Wg1,
                         const float* __restrict__ bg1, const float* __restrict__ Wg2,
                         const float* __restrict__ bg2, const int* __restrict__ flags,
                         int* __restrict__ tidx, float* __restrict__ tprob){
  __shared__ float cs[1024];
  __shared__ double hs[1024];
  __shared__ double red[256];
  const int tid = threadIdx.x, wv = tid>>6, ln = tid&63;
  for (int t = blockIdx.x; t < B_; t += gridDim.x){
    if (!flags[t]) continue;
    __syncthreads();
    for (int i = tid; i < 1024; i += 256) cs[i] = cond[(size_t)t*1024 + i];
    __syncthreads();
    for (int jj = 0; jj < 256; ++jj){
      int j = wv*256 + jj;
      double a = 0.0;
      #pragma unroll
      for (int k2 = 0; k2 < 16; ++k2){
        int c = ln + 64*k2;
        a += (double)cs[c] * (double)Wg1[(size_t)j*1024 + c];
      }
      #pragma unroll
      for (int off = 32; off > 0; off >>= 1) a += __shfl_down(a, off);
      if (ln == 0){
        double z = a + (double)bg1[j];
        hs[j] = 0.5*z*(1.0 + erf(z*0.70710678118654752440));
      }
    }
    __syncthreads();
    {
      int e2 = tid & 15, chk = tid >> 4;
      double a = 0.0;
      for (int jj = 0; jj < 64; ++jj){
        int j = chk*64 + jj;
        a += hs[j] * (double)Wg2[(size_t)e2*1024 + j];
      }
      red[tid] = a;
    }
    __syncthreads();
    if (tid < 16){
      double a = 0.0;
      for (int c2 = 0; c2 < 16; ++c2) a += red[c2*16 + tid];
      red[tid] = a + (double)bg2[tid];
    }
    __syncthreads();
    if (tid == 0){
      double v0=-1e300,v1=-1e300,v2=-1e300,v3=-1e300; int x0=0,x1=0,x2=0,x3=0;
      for (int e2=0;e2<16;e2++){
        double le = red[e2];
        if (le > v0){ v3=v2;x3=x2; v2=v1;x2=x1; v1=v0;x1=x0; v0=le;x0=e2; }
        else if (le > v1){ v3=v2;x3=x2; v2=v1;x2=x1; v1=le;x1=e2; }
        else if (le > v2){ v3=v2;x3=x2; v2=le;x2=e2; }
        else if (le > v3){ v3=le;x3=e2; }
      }
      double den = 0.0;
      for (int e2=0;e2<16;e2++) den += exp(red[e2] - v0);
      tidx[t*3+0]=x0; tidx[t*3+1]=x1; tidx[t*3+2]=x2;
      tprob[t*3+0]=(float)(1.0/den);
      tprob[t*3+1]=(float)(exp(v1-v0)/den);
      tprob[t*3+2]=(float)(exp(v2-v0)/den);
    }
    __syncthreads();
  }
}

// ---------- bucket building ----------
__global__ void k_zero(int* counts){ if (threadIdx.x < 48) counts[threadIdx.x] = 0; }

__global__ void k_build(const int* __restrict__ tidx, const float* __restrict__ tprob,
                        int* __restrict__ counts, int2* __restrict__ lists){
  int t = blockIdx.x*256 + threadIdx.x;
  if (t >= B_) return;
  #pragma unroll
  for (int s=0;s<3;s++){
    int e = tidx[t*3+s];
    float p = tprob[t*3+s];
    int pos = atomicAdd(&counts[s*16+e], 1);
    if (pos < 4096) lists[(size_t)(s*16+e)*4096 + pos] = make_int2(t, __float_as_int(p));
  }
}

__global__ void k_pad(const int* __restrict__ counts, int2* __restrict__ lists){
  int b = threadIdx.x;
  if (b >= 48) return;
  int n = counts[b]; if (n > 4096) n = 4096;
  int np = (n + 127) & ~127;
  for (int i=n;i<np;i++) lists[(size_t)b*4096 + i] = make_int2(0, 0);
}

// ---------- generalist GEMM: out = x@Wgen^T + bgen + sum_k p_k*be[e_k] ----------
__global__ __launch_bounds__(256) void k_gen_gemm(
    const uint16_t* __restrict__ xb, const uint16_t* __restrict__ wall,
    const float* __restrict__ be, const float* __restrict__ bgen,
    const int* __restrict__ tidx, const float* __restrict__ tprob,
    float* __restrict__ out){
  __shared__ uint16_t As[128*64], Bs[128*64];
  const int tid = threadIdx.x, wv = tid>>6, ln = tid&63;
  const int mt = blockIdx.x>>3, nt = blockIdx.x&7;
  const int wr = wv>>1, wc = wv&1, lr = ln&15, lk = ln>>4;
  f32x4 acc[4][4];
  f32x4 z4 = {0.f,0.f,0.f,0.f};
  #pragma unroll
  for (int m=0;m<4;m++){
    #pragma unroll
    for (int n=0;n<4;n++) acc[m][n] = z4;
  }
  const uint16_t* Bsrc = wall + (size_t)16*1024*1024;
  const int srow = ln>>3, scol = (ln&7)*8;
  for (int ks=0; ks<16; ++ks){
    const int k0 = ks*64;
    __syncthreads();
    #pragma unroll
    for (int c2=0;c2<4;c2++){
      int ch = wv + c2*4;
      int r = ch*8 + srow;
      glds16(xb + (size_t)(mt*128 + r)*1024 + k0 + scol, (char*)As + ch*1024);
      glds16(Bsrc + (size_t)(nt*128 + r)*1024 + k0 + scol, (char*)Bs + ch*1024);
    }
    asm volatile("s_waitcnt vmcnt(0)" ::: "memory");
    __syncthreads();
    #pragma unroll
    for (int kk=0;kk<2;kk++){
      bf16x8 a[4], b[4];
      #pragma unroll
      for (int m=0;m<4;m++) a[m] = *(const bf16x8*)&As[(wr*64+m*16+lr)*64 + kk*32 + lk*8];
      #pragma unroll
      for (int n=0;n<4;n++) b[n] = *(const bf16x8*)&Bs[(wc*64+n*16+lr)*64 + kk*32 + lk*8];
      #pragma unroll
      for (int m=0;m<4;m++){
        #pragma unroll
        for (int n=0;n<4;n++)
          acc[m][n] = __builtin_amdgcn_mfma_f32_16x16x32_bf16(a[m], b[n], acc[m][n], 0,0,0);
      }
    }
  }
  #pragma unroll
  for (int m=0;m<4;m++){
    #pragma unroll
    for (int j=0;j<4;j++){
      int r = mt*128 + wr*64 + m*16 + lk*4 + j;
      int i0=tidx[r*3+0], i1=tidx[r*3+1], i2=tidx[r*3+2];
      float p0=tprob[r*3+0], p1=tprob[r*3+1], p2=tprob[r*3+2];
      #pragma unroll
      for (int n=0;n<4;n++){
        int c = nt*128 + wc*64 + n*16 + lr;
        out[(size_t)r*1024 + c] = acc[m][n][j] + bgen[c]
            + p0*be[i0*1024+c] + p1*be[i1*1024+c] + p2*be[i2*1024+c];
      }
    }
  }
}

// ---------- per-slot gathered expert GEMM: out[token] += p * (x[token] @ We[e]^T) ----------
__global__ __launch_bounds__(256) void k_slot_gemm(
    const uint16_t* __restrict__ xb, const uint16_t* __restrict__ wall,
    const int2* __restrict__ lists, const int* __restrict__ counts,
    const int slot, float* __restrict__ out){
  __shared__ uint16_t As[128*64], Bs[128*64];
  __shared__ int2 ent[128];
  const int bid = blockIdx.x;
  const int e = bid>>8, mtl = (bid>>3)&31, nt = bid&7;
  const int cnt = counts[slot*16 + e];
  const int npad = (cnt + 127) & ~127;
  if (mtl*128 >= npad) return;
  const int tid = threadIdx.x, wv = tid>>6, ln = tid&63;
  const int wr = wv>>1, wc = wv&1, lr = ln&15, lk = ln>>4;
  if (tid < 128) ent[tid] = lists[(size_t)(slot*16+e)*4096 + mtl*128 + tid];
  __syncthreads();
  const uint16_t* Bsrc = wall + (size_t)e*1024*1024;
  f32x4 acc[4][4];
  f32x4 z4 = {0.f,0.f,0.f,0.f};
  #pragma unroll
  for (int m=0;m<4;m++){
    #pragma unroll
    for (int n=0;n<4;n++) acc[m][n] = z4;
  }
  const int srow = ln>>3, scol = (ln&7)*8;
  for (int ks=0; ks<16; ++ks){
    const int k0 = ks*64;
    __syncthreads();
    #pragma unroll
    for (int c2=0;c2<4;c2++){
      int ch = wv + c2*4;
      int r = ch*8 + srow;
      glds16(xb + (size_t)ent[r].x*1024 + k0 + scol, (char*)As + ch*1024);
      glds16(Bsrc + (size_t)(nt*128 + r)*1024 + k0 + scol, (char*)Bs + ch*1024);
    }
    asm volatile("s_waitcnt vmcnt(0)" ::: "memory");
    __syncthreads();
    #pragma unroll
    for (int kk=0;kk<2;kk++){
      bf16x8 a[4], b[4];
      #pragma unroll
      for (int m=0;m<4;m++) a[m] = *(const bf16x8*)&As[(wr*64+m*16+lr)*64 + kk*32 + lk*8];
      #pragma unroll
      for (int n=0;n<4;n++) b[n] = *(const bf16x8*)&Bs[(wc*64+n*16+lr)*64 + kk*32 + lk*8];
      #pragma unroll
      for (int m=0;m<4;m++){
        #pragma unroll
        for (int n=0;n<4;n++)
          acc[m][n] = __builtin_amdgcn_mfma_f32_16x16x32_bf16(a[m], b[n], acc[m][n], 0,0,0);
      }
    }
  }
  #pragma unroll
  for (int m=0;m<4;m++){
    #pragma unroll
    for (int j=0;j<4;j++){
      int rl = wr*64 + m*16 + lk*4 + j;
      int2 en = ent[rl];
      float p = __int_as_float(en.y);
      if (p != 0.0f){
        size_t rb = (size_t)en.x*1024;
        #pragma unroll
        for (int n=0;n<4;n++){
          int c = nt*128 + wc*64 + n*16 + lr;
          out[rb + c] += p*acc[m][n][j];
        }
      }
    }
  }
}

// ---------- launch ----------
extern "C" void kernel_launch(void* const* d_in, const int* in_sizes, int n_in,
                              void* d_out, int out_size, void* d_ws, size_t ws_size,
                              hipStream_t stream) {
  (void)in_sizes; (void)n_in; (void)out_size; (void)ws_size;
  const float* x    = (const float*)d_in[0];
  const float* cond = (const float*)d_in[1];
  const float* We   = (const float*)d_in[2];
  const float* be   = (const float*)d_in[3];
  const float* Wg1  = (const float*)d_in[4];
  const float* bg1  = (const float*)d_in[5];
  const float* Wg2  = (const float*)d_in[6];
  const float* bg2  = (const float*)d_in[7];
  const float* Wgen = (const float*)d_in[8];
  const float* bgen = (const float*)d_in[9];
  float* out = (float*)d_out;
  char* ws = (char*)d_ws;

  uint16_t* xb    = (uint16_t*)(ws + 0);
  uint16_t* wall  = (uint16_t*)(ws + 33554432);
  float*    hbuf  = (float*)   (ws + 69206016);
  uint16_t* chi   = (uint16_t*)(ws + 136314880);
  uint16_t* clo   = (uint16_t*)(ws + 169869312);
  uint16_t* g1h   = (uint16_t*)(ws + 203423744);
  uint16_t* g1l   = (uint16_t*)(ws + 205520896);
  int*      tidx  = (int*)     (ws + 207618048);
  float*    tprob = (float*)   (ws + 207814656);
  int*      flags = (int*)     (ws + 208011264);
  int*      counts= (int*)     (ws + 208076800);
  int2*     lists = (int2*)    (ws + 208077056);

  // casts / splits
  k_cast<<<16384,256,0,stream>>>((const float4*)x, (ushort4*)xb, 4194304);
  k_cast_wall<<<17408,256,0,stream>>>((const float4*)We, (const float4*)Wgen, (ushort4*)wall);
  k_split<<<16384,256,0,stream>>>((const float4*)cond, (ushort4*)chi, (ushort4*)clo, 4194304);
  k_split<<<1024,256,0,stream>>>((const float4*)Wg1, (ushort4*)g1h, (ushort4*)g1l, 262144);

  // gate
  k_gate_gemm<<<1024,256,0,stream>>>(chi, clo, g1h, g1l, bg1, hbuf);
  k_gate2<<<4096,256,0,stream>>>(hbuf, Wg2, bg2, tidx, tprob, flags);
  k_refine<<<64,256,0,stream>>>(cond, Wg1, bg1, Wg2, bg2, flags, tidx, tprob);

  // buckets
  k_zero<<<1,64,0,stream>>>(counts);
  k_build<<<64,256,0,stream>>>(tidx, tprob, counts, lists);
  k_pad<<<1,64,0,stream>>>(counts, lists);

  // main compute
  k_gen_gemm<<<1024,256,0,stream>>>(xb, wall, be, bgen, tidx, tprob, out);
  for (int s=0;s<3;s++)
    k_slot_gemm<<<4096,256,0,stream>>>(xb, wall, lists, counts, s, out);
}

// Round 2
// 1057.049 us; speedup vs baseline: 8.1213x; 8.1213x over previous
//
#include <hip/hip_runtime.h>
#include <hip/hip_bf16.h>
#include <stdint.h>

typedef short bf16x8 __attribute__((ext_vector_type(8)));
typedef float f32x4 __attribute__((ext_vector_type(4)));

#define B_ 16384
#define D_ 1024
#define H_ 1024
#define E_ 16
#define C_ 1024
#define TAU 1.0e-3f

// ---------- helpers ----------
__device__ __forceinline__ uint16_t f2bf(float f){
  uint32_t u = __float_as_uint(f);
  return (uint16_t)((u + 0x7FFFu + ((u >> 16) & 1u)) >> 16);
}
__device__ __forceinline__ float bf2f(uint16_t h){
  return __uint_as_float(((uint32_t)h) << 16);
}
__device__ __forceinline__ void glds16(const void* g, void* l){
  typedef __attribute__((address_space(1))) unsigned int* gp_t;
  typedef __attribute__((address_space(3))) unsigned int* lp_t;
  __builtin_amdgcn_global_load_lds((gp_t)(uintptr_t)g, (lp_t)(uintptr_t)l, 16, 0, 0);
}

// ---------- cast / split kernels ----------
__global__ void k_cast(const float4* __restrict__ src, ushort4* __restrict__ dst, int n4){
  int i = blockIdx.x*256 + threadIdx.x;
  if (i >= n4) return;
  float4 v = src[i];
  ushort4 o; o.x=f2bf(v.x); o.y=f2bf(v.y); o.z=f2bf(v.z); o.w=f2bf(v.w);
  dst[i] = o;
}

__global__ void k_cast_wall(const float4* __restrict__ We, const float4* __restrict__ Wgen,
                            ushort4* __restrict__ dst){
  int i = blockIdx.x*256 + threadIdx.x;
  if (i >= 4456448) return;
  float4 v = (i < 4194304) ? We[i] : Wgen[i - 4194304];
  ushort4 o; o.x=f2bf(v.x); o.y=f2bf(v.y); o.z=f2bf(v.z); o.w=f2bf(v.w);
  dst[i] = o;
}

__global__ void k_split(const float4* __restrict__ src, ushort4* __restrict__ hi,
                        ushort4* __restrict__ lo, int n4){
  int i = blockIdx.x*256 + threadIdx.x;
  if (i >= n4) return;
  float4 v = src[i];
  ushort4 h, l;
  h.x=f2bf(v.x); l.x=f2bf(v.x - bf2f(h.x));
  h.y=f2bf(v.y); l.y=f2bf(v.y - bf2f(h.y));
  h.z=f2bf(v.z); l.z=f2bf(v.z - bf2f(h.z));
  h.w=f2bf(v.w); l.w=f2bf(v.w - bf2f(h.w));
  hi[i]=h; lo[i]=l;
}

// ---------- Wg1 transpose (f32): Wg1T[c][j] = Wg1[j][c] ----------
__global__ __launch_bounds__(256) void k_transpose(const float* __restrict__ src,
                                                   float* __restrict__ dst){
  __shared__ float tile[64][65];
  const int bx = (blockIdx.x & 15) * 64;   // col base (c)
  const int by = (blockIdx.x >> 4) * 64;   // row base (j)
  const int tx = threadIdx.x & 63, ty = threadIdx.x >> 6;
  #pragma unroll
  for (int r = 0; r < 64; r += 4)
    tile[r + ty][tx] = src[(size_t)(by + r + ty)*1024 + bx + tx];
  __syncthreads();
  #pragma unroll
  for (int r = 0; r < 64; r += 4)
    dst[(size_t)(bx + r + ty)*1024 + by + tx] = tile[tx][r + ty];
}

// ---------- gate GEMM1: z = cond @ Wg1^T + bg1, h = gelu(z), split-bf16 x3 ----------
__global__ __launch_bounds__(256) void k_gate_gemm(
    const uint16_t* __restrict__ Ah_g, const uint16_t* __restrict__ Al_g,
    const uint16_t* __restrict__ Bh_g, const uint16_t* __restrict__ Bl_g,
    const float* __restrict__ bg1, float* __restrict__ hbuf){
  __shared__ uint16_t Ah[128*32], Al[128*32], Bh[128*32], Bl[128*32];
  const int tid = threadIdx.x, wv = tid>>6, ln = tid&63;
  const int mt = blockIdx.x>>3, nt = blockIdx.x&7;
  const int wr = wv>>1, wc = wv&1, lr = ln&15, lk = ln>>4;
  f32x4 acc[4][4];
  f32x4 z4 = {0.f,0.f,0.f,0.f};
  #pragma unroll
  for (int m=0;m<4;m++){
    #pragma unroll
    for (int n=0;n<4;n++) acc[m][n] = z4;
  }
  const int rA = mt*128, rB = nt*128;
  const int srow = (ln>>2), scol = (ln&3)*8;
  for (int ks=0; ks<32; ++ks){
    const int k0 = ks*32;
    __syncthreads();
    #pragma unroll
    for (int c2=0;c2<2;c2++){
      int ch = wv + c2*4;
      int r = ch*16 + srow;
      size_t aoff = (size_t)(rA + r)*1024 + k0 + scol;
      size_t boff = (size_t)(rB + r)*1024 + k0 + scol;
      glds16(Ah_g + aoff, (char*)Ah + ch*1024);
      glds16(Al_g + aoff, (char*)Al + ch*1024);
      glds16(Bh_g + boff, (char*)Bh + ch*1024);
      glds16(Bl_g + boff, (char*)Bl + ch*1024);
    }
    asm volatile("s_waitcnt vmcnt(0)" ::: "memory");
    __syncthreads();
    bf16x8 ah[4], al[4], bh[4], bl[4];
    #pragma unroll
    for (int m=0;m<4;m++){
      int r = wr*64 + m*16 + lr;
      ah[m] = *(const bf16x8*)&Ah[r*32 + lk*8];
      al[m] = *(const bf16x8*)&Al[r*32 + lk*8];
    }
    #pragma unroll
    for (int n=0;n<4;n++){
      int r = wc*64 + n*16 + lr;
      bh[n] = *(const bf16x8*)&Bh[r*32 + lk*8];
      bl[n] = *(const bf16x8*)&Bl[r*32 + lk*8];
    }
    #pragma unroll
    for (int m=0;m<4;m++){
      #pragma unroll
      for (int n=0;n<4;n++){
        acc[m][n] = __builtin_amdgcn_mfma_f32_16x16x32_bf16(ah[m], bh[n], acc[m][n], 0,0,0);
        acc[m][n] = __builtin_amdgcn_mfma_f32_16x16x32_bf16(ah[m], bl[n], acc[m][n], 0,0,0);
        acc[m][n] = __builtin_amdgcn_mfma_f32_16x16x32_bf16(al[m], bh[n], acc[m][n], 0,0,0);
      }
    }
  }
  #pragma unroll
  for (int m=0;m<4;m++){
    #pragma unroll
    for (int j=0;j<4;j++){
      int r = rA + wr*64 + m*16 + lk*4 + j;
      #pragma unroll
      for (int n=0;n<4;n++){
        int c = rB + wc*64 + n*16 + lr;
        float z = acc[m][n][j] + bg1[c];
        hbuf[(size_t)r*1024 + c] = 0.5f*z*(1.0f + erff(z*0.70710678118654752f));
      }
    }
  }
}

// ---------- gate stage 2: logits, softmax, top-3, ambiguity compaction ----------
__global__ __launch_bounds__(256) void k_gate2(
    const float* __restrict__ hbuf, const float* __restrict__ Wg2,
    const float* __restrict__ bg2, int* __restrict__ tidx,
    float* __restrict__ tprob, int* __restrict__ rcount,
    int* __restrict__ rlist){
  __shared__ float w2[16*1024];
  const int tid = threadIdx.x;
  for (int i = tid; i < 4096; i += 256)
    ((float4*)w2)[i] = ((const float4*)Wg2)[i];
  __syncthreads();
  const int wv = tid>>6, ln = tid&63;
  const int t = blockIdx.x*4 + wv;
  float s[16];
  #pragma unroll
  for (int e2=0;e2<16;e2++) s[e2]=0.f;
  #pragma unroll
  for (int i=0;i<4;i++){
    float4 hv = *(const float4*)&hbuf[(size_t)t*1024 + i*256 + ln*4];
    #pragma unroll
    for (int e2=0;e2<16;e2++){
      float4 w = *(const float4*)&w2[e2*1024 + i*256 + ln*4];
      s[e2] += hv.x*w.x + hv.y*w.y + hv.z*w.z + hv.w*w.w;
    }
  }
  #pragma unroll
  for (int e2=0;e2<16;e2++){
    float v = s[e2];
    #pragma unroll
    for (int off=32; off>0; off>>=1) v += __shfl_xor(v, off);
    s[e2] = v + bg2[e2];
  }
  float v0=-1e30f,v1=-1e30f,v2=-1e30f,v3=-1e30f; int x0=0,x1=0,x2=0,x3=0;
  #pragma unroll
  for (int e2=0;e2<16;e2++){
    float le = s[e2];
    if (le > v0){ v3=v2;x3=x2; v2=v1;x2=x1; v1=v0;x1=x0; v0=le;x0=e2; }
    else if (le > v1){ v3=v2;x3=x2; v2=v1;x2=x1; v1=le;x1=e2; }
    else if (le > v2){ v3=v2;x3=x2; v2=le;x2=e2; }
    else if (le > v3){ v3=le;x3=e2; }
  }
  float den = 0.f;
  #pragma unroll
  for (int e2=0;e2<16;e2++) den += expf(s[e2]-v0);
  if (ln==0){
    tidx[t*3+0]=x0; tidx[t*3+1]=x1; tidx[t*3+2]=x2;
    tprob[t*3+0]=1.0f/den;
    tprob[t*3+1]=expf(v1-v0)/den;
    tprob[t*3+2]=expf(v2-v0)/den;
    if ((v2 - v3) < TAU){
      int p = atomicAdd(rcount, 1);
      rlist[p] = t;
    }
  }
}

// ---------- gate refine (f64) for boundary-ambiguous tokens ----------
// one token per block (compacted list), reduction-free: thread tid owns
// rows j = tid, tid+256, tid+512, tid+768; coalesced Wg1T reads.
__global__ __launch_bounds__(256) void k_refine(
    const float* __restrict__ cond, const float* __restrict__ Wg1T,
    const float* __restrict__ bg1, const float* __restrict__ Wg2,
    const float* __restrict__ bg2, const int* __restrict__ rcount,
    const int* __restrict__ rlist,
    int* __restrict__ tidx, float* __restrict__ tprob){
  __shared__ float cs[1024];
  __shared__ double hs[1024];
  __shared__ double red[256];
  const int tid = threadIdx.x;
  const int nf = rcount[0];
  for (int idx = blockIdx.x; idx < nf; idx += gridDim.x){
    const int t = rlist[idx];
    __syncthreads();
    for (int i = tid; i < 1024; i += 256) cs[i] = cond[(size_t)t*1024 + i];
    __syncthreads();
    double a0=0.0, a1=0.0, a2=0.0, a3=0.0;
    for (int c = 0; c < 1024; ++c){
      double cv = (double)cs[c];
      const float* wr = &Wg1T[(size_t)c*1024 + tid];
      a0 += cv * (double)wr[0];
      a1 += cv * (double)wr[256];
      a2 += cv * (double)wr[512];
      a3 += cv * (double)wr[768];
    }
    {
      const double is2 = 0.70710678118654752440;
      double z;
      z = a0 + (double)bg1[tid];       hs[tid]     = 0.5*z*(1.0+erf(z*is2));
      z = a1 + (double)bg1[tid+256];   hs[tid+256] = 0.5*z*(1.0+erf(z*is2));
      z = a2 + (double)bg1[tid+512];   hs[tid+512] = 0.5*z*(1.0+erf(z*is2));
      z = a3 + (double)bg1[tid+768];   hs[tid+768] = 0.5*z*(1.0+erf(z*is2));
    }
    __syncthreads();
    {
      int e2 = tid & 15, chk = tid >> 4;
      double a = 0.0;
      for (int jj = 0; jj < 64; ++jj){
        int j = chk*64 + jj;
        a += hs[j] * (double)Wg2[(size_t)e2*1024 + j];
      }
      red[tid] = a;
    }
    __syncthreads();
    if (tid < 16){
      double a = 0.0;
      for (int c2 = 0; c2 < 16; ++c2) a += red[c2*16 + tid];
      red[tid] = a + (double)bg2[tid];
    }
    __syncthreads();
    if (tid == 0){
      double v0=-1e300,v1=-1e300,v2=-1e300; int x0=0,x1=0,x2=0;
      for (int e2=0;e2<16;e2++){
        double le = red[e2];
        if (le > v0){ v2=v1;x2=x1; v1=v0;x1=x0; v0=le;x0=e2; }
        else if (le > v1){ v2=v1;x2=x1; v1=le;x1=e2; }
        else if (le > v2){ v2=le;x2=e2; }
      }
      double den = 0.0;
      for (int e2=0;e2<16;e2++) den += exp(red[e2] - v0);
      tidx[t*3+0]=x0; tidx[t*3+1]=x1; tidx[t*3+2]=x2;
      tprob[t*3+0]=(float)(1.0/den);
      tprob[t*3+1]=(float)(exp(v1-v0)/den);
      tprob[t*3+2]=(float)(exp(v2-v0)/den);
    }
    __syncthreads();
  }
}

// ---------- bucket building ----------
__global__ void k_zero(int* counts){ if (threadIdx.x < 64) counts[threadIdx.x] = 0; }

__global__ void k_build(const int* __restrict__ tidx, const float* __restrict__ tprob,
                        int* __restrict__ counts, int2* __restrict__ lists){
  int t = blockIdx.x*256 + threadIdx.x;
  if (t >= B_) return;
  #pragma unroll
  for (int s=0;s<3;s++){
    int e = tidx[t*3+s];
    float p = tprob[t*3+s];
    int pos = atomicAdd(&counts[s*16+e], 1);
    if (pos < 4096) lists[(size_t)(s*16+e)*4096 + pos] = make_int2(t, __float_as_int(p));
  }
}

__global__ void k_pad(const int* __restrict__ counts, int2* __restrict__ lists){
  int b = threadIdx.x;
  if (b >= 48) return;
  int n = counts[b]; if (n > 4096) n = 4096;
  int np = (n + 127) & ~127;
  for (int i=n;i<np;i++) lists[(size_t)b*4096 + i] = make_int2(0, 0);
}

// ---------- generalist GEMM: out = x@Wgen^T + bgen + sum_k p_k*be[e_k] ----------
__global__ __launch_bounds__(256) void k_gen_gemm(
    const uint16_t* __restrict__ xb, const uint16_t* __restrict__ wall,
    const float* __restrict__ be, const float* __restrict__ bgen,
    const int* __restrict__ tidx, const float* __restrict__ tprob,
    float* __restrict__ out){
  __shared__ uint16_t As[128*64], Bs[128*64];
  const int tid = threadIdx.x, wv = tid>>6, ln = tid&63;
  const int mt = blockIdx.x>>3, nt = blockIdx.x&7;
  const int wr = wv>>1, wc = wv&1, lr = ln&15, lk = ln>>4;
  f32x4 acc[4][4];
  f32x4 z4 = {0.f,0.f,0.f,0.f};
  #pragma unroll
  for (int m=0;m<4;m++){
    #pragma unroll
    for (int n=0;n<4;n++) acc[m][n] = z4;
  }
  const uint16_t* Bsrc = wall + (size_t)16*1024*1024;
  const int srow = ln>>3, scol = (ln&7)*8;
  for (int ks=0; ks<16; ++ks){
    const int k0 = ks*64;
    __syncthreads();
    #pragma unroll
    for (int c2=0;c2<4;c2++){
      int ch = wv + c2*4;
      int r = ch*8 + srow;
      glds16(xb + (size_t)(mt*128 + r)*1024 + k0 + scol, (char*)As + ch*1024);
      glds16(Bsrc + (size_t)(nt*128 + r)*1024 + k0 + scol, (char*)Bs + ch*1024);
    }
    asm volatile("s_waitcnt vmcnt(0)" ::: "memory");
    __syncthreads();
    #pragma unroll
    for (int kk=0;kk<2;kk++){
      bf16x8 a[4], b[4];
      #pragma unroll
      for (int m=0;m<4;m++) a[m] = *(const bf16x8*)&As[(wr*64+m*16+lr)*64 + kk*32 + lk*8];
      #pragma unroll
      for (int n=0;n<4;n++) b[n] = *(const bf16x8*)&Bs[(wc*64+n*16+lr)*64 + kk*32 + lk*8];
      #pragma unroll
      for (int m=0;m<4;m++){
        #pragma unroll
        for (int n=0;n<4;n++)
          acc[m][n] = __builtin_amdgcn_mfma_f32_16x16x32_bf16(a[m], b[n], acc[m][n], 0,0,0);
      }
    }
  }
  #pragma unroll
  for (int m=0;m<4;m++){
    #pragma unroll
    for (int j=0;j<4;j++){
      int r = mt*128 + wr*64 + m*16 + lk*4 + j;
      int i0=tidx[r*3+0], i1=tidx[r*3+1], i2=tidx[r*3+2];
      float p0=tprob[r*3+0], p1=tprob[r*3+1], p2=tprob[r*3+2];
      #pragma unroll
      for (int n=0;n<4;n++){
        int c = nt*128 + wc*64 + n*16 + lr;
        out[(size_t)r*1024 + c] = acc[m][n][j] + bgen[c]
            + p0*be[i0*1024+c] + p1*be[i1*1024+c] + p2*be[i2*1024+c];
      }
    }
  }
}

// ---------- per-slot gathered expert GEMM: out[token] += p * (x[token] @ We[e]^T) ----------
__global__ __launch_bounds__(256) void k_slot_gemm(
    const uint16_t* __restrict__ xb, const uint16_t* __restrict__ wall,
    const int2* __restrict__ lists, const int* __restrict__ counts,
    const int slot, float* __restrict__ out){
  __shared__ uint16_t As[128*64], Bs[128*64];
  __shared__ int2 ent[128];
  const int bid = blockIdx.x;
  const int e = bid>>8, mtl = (bid>>3)&31, nt = bid&7;
  const int cnt = counts[slot*16 + e];
  const int npad = (cnt + 127) & ~127;
  if (mtl*128 >= npad) return;
  const int tid = threadIdx.x, wv = tid>>6, ln = tid&63;
  const int wr = wv>>1, wc = wv&1, lr = ln&15, lk = ln>>4;
  if (tid < 128) ent[tid] = lists[(size_t)(slot*16+e)*4096 + mtl*128 + tid];
  __syncthreads();
  const uint16_t* Bsrc = wall + (size_t)e*1024*1024;
  f32x4 acc[4][4];
  f32x4 z4 = {0.f,0.f,0.f,0.f};
  #pragma unroll
  for (int m=0;m<4;m++){
    #pragma unroll
    for (int n=0;n<4;n++) acc[m][n] = z4;
  }
  const int srow = ln>>3, scol = (ln&7)*8;
  for (int ks=0; ks<16; ++ks){
    const int k0 = ks*64;
    __syncthreads();
    #pragma unroll
    for (int c2=0;c2<4;c2++){
      int ch = wv + c2*4;
      int r = ch*8 + srow;
      glds16(xb + (size_t)ent[r].x*1024 + k0 + scol, (char*)As + ch*1024);
      glds16(Bsrc + (size_t)(nt*128 + r)*1024 + k0 + scol, (char*)Bs + ch*1024);
    }
    asm volatile("s_waitcnt vmcnt(0)" ::: "memory");
    __syncthreads();
    #pragma unroll
    for (int kk=0;kk<2;kk++){
      bf16x8 a[4], b[4];
      #pragma unroll
      for (int m=0;m<4;m++) a[m] = *(const bf16x8*)&As[(wr*64+m*16+lr)*64 + kk*32 + lk*8];
      #pragma unroll
      for (int n=0;n<4;n++) b[n] = *(const bf16x8*)&Bs[(wc*64+n*16+lr)*64 + kk*32 + lk*8];
      #pragma unroll
      for (int m=0;m<4;m++){
        #pragma unroll
        for (int n=0;n<4;n++)
          acc[m][n] = __builtin_amdgcn_mfma_f32_16x16x32_bf16(a[m], b[n], acc[m][n], 0,0,0);
      }
    }
  }
  #pragma unroll
  for (int m=0;m<4;m++){
    #pragma unroll
    for (int j=0;j<4;j++){
      int rl = wr*64 + m*16 + lk*4 + j;
      int2 en = ent[rl];
      float p = __int_as_float(en.y);
      if (p != 0.0f){
        size_t rb = (size_t)en.x*1024;
        #pragma unroll
        for (int n=0;n<4;n++){
          int c = nt*128 + wc*64 + n*16 + lr;
          out[rb + c] += p*acc[m][n][j];
        }
      }
    }
  }
}

// ---------- launch ----------
extern "C" void kernel_launch(void* const* d_in, const int* in_sizes, int n_in,
                              void* d_out, int out_size, void* d_ws, size_t ws_size,
                              hipStream_t stream) {
  (void)in_sizes; (void)n_in; (void)out_size; (void)ws_size;
  const float* x    = (const float*)d_in[0];
  const float* cond = (const float*)d_in[1];
  const float* We   = (const float*)d_in[2];
  const float* be   = (const float*)d_in[3];
  const float* Wg1  = (const float*)d_in[4];
  const float* bg1  = (const float*)d_in[5];
  const float* Wg2  = (const float*)d_in[6];
  const float* bg2  = (const float*)d_in[7];
  const float* Wgen = (const float*)d_in[8];
  const float* bgen = (const float*)d_in[9];
  float* out = (float*)d_out;
  char* ws = (char*)d_ws;

  uint16_t* xb    = (uint16_t*)(ws + 0);
  uint16_t* wall  = (uint16_t*)(ws + 33554432);
  float*    hbuf  = (float*)   (ws + 69206016);
  float*    Wg1T  = (float*)   (ws + 69206016);   // aliases hbuf; written after gate2
  uint16_t* chi   = (uint16_t*)(ws + 136314880);
  uint16_t* clo   = (uint16_t*)(ws + 169869312);
  uint16_t* g1h   = (uint16_t*)(ws + 203423744);
  uint16_t* g1l   = (uint16_t*)(ws + 205520896);
  int*      tidx  = (int*)     (ws + 207618048);
  float*    tprob = (float*)   (ws + 207814656);
  int*      rlist = (int*)     (ws + 208011264);
  int*      counts= (int*)     (ws + 208076800);  // [0..47] buckets, [48] = rcount
  int2*     lists = (int2*)    (ws + 208077056);
  int*      rcount= counts + 48;

  // casts / splits
  k_cast<<<16384,256,0,stream>>>((const float4*)x, (ushort4*)xb, 4194304);
  k_cast_wall<<<17408,256,0,stream>>>((const float4*)We, (const float4*)Wgen, (ushort4*)wall);
  k_split<<<16384,256,0,stream>>>((const float4*)cond, (ushort4*)chi, (ushort4*)clo, 4194304);
  k_split<<<1024,256,0,stream>>>((const float4*)Wg1, (ushort4*)g1h, (ushort4*)g1l, 262144);
  k_zero<<<1,64,0,stream>>>(counts);

  // gate
  k_gate_gemm<<<1024,256,0,stream>>>(chi, clo, g1h, g1l, bg1, hbuf);
  k_gate2<<<4096,256,0,stream>>>(hbuf, Wg2, bg2, tidx, tprob, rcount, rlist);
  k_transpose<<<256,256,0,stream>>>(Wg1, Wg1T);
  k_refine<<<1024,256,0,stream>>>(cond, Wg1T, bg1, Wg2, bg2, rcount, rlist, tidx, tprob);

  // buckets
  k_build<<<64,256,0,stream>>>(tidx, tprob, counts, lists);
  k_pad<<<1,64,0,stream>>>(counts, lists);

  // main compute
  k_gen_gemm<<<1024,256,0,stream>>>(xb, wall, be, bgen, tidx, tprob, out);
  for (int s=0;s<3;s++)
    k_slot_gemm<<<4096,256,0,stream>>>(xb, wall, lists, counts, s, out);
}